// Round 6
// baseline (8299.073 us; speedup 1.0000x reference)
//
#include <hip/hip_runtime.h>

#define T_STEPS 512
#define D_IN    32
#define H       64
#define NB      4     // batch elements per block

// ---- DPP cross-lane add: sum over the 4 lanes of each quad (chunk id = lane&3) ----
template<int CTRL>
__device__ __forceinline__ float dpp_add(float v) {
    int m = __builtin_amdgcn_update_dpp(0, __float_as_int(v), CTRL, 0xf, 0xf, true);
    return v + __int_as_float(m);
}
__device__ __forceinline__ float red4(float v) {
    v = dpp_add<0xB1>(v);   // quad_perm [1,0,3,2] : + lane^1
    v = dpp_add<0x4E>(v);   // quad_perm [2,3,0,1] : + lane^2
    return v;
}

// select a[c] with loop-invariant c (3 cndmask; no dynamic reg indexing)
__device__ __forceinline__ float sel4(const float* a, int c) {
    float r = a[0];
    r = (c == 1) ? a[1] : r;
    r = (c == 2) ? a[2] : r;
    r = (c == 3) ? a[3] : r;
    return r;
}

__device__ __forceinline__ float sigf(float x) {
    return 1.0f / (1.0f + __expf(-x));
}
__device__ __forceinline__ float tanhf_(float x) {
    float e = __expf(2.0f * x);
    return 1.0f - 2.0f / (e + 1.0f);
}

__global__ __launch_bounds__(512, 2)
void lstm2_fused(const float* __restrict__ x,
                 const float* __restrict__ Wih0, const float* __restrict__ Whh0,
                 const float* __restrict__ bih0, const float* __restrict__ bhh0,
                 const float* __restrict__ Wih1, const float* __restrict__ Whh1,
                 const float* __restrict__ bih1, const float* __restrict__ bhh1,
                 const float* __restrict__ Wfc,  const float* __restrict__ bfc,
                 float* __restrict__ out)
{
    // Double-buffered (parity) state. One barrier per step.
    // L0 input: vin[p][b] = { x_t (32) , h0 (64) }; chunk c reads float4 at
    //   24c+4q -> bank-quads {0,24,16,8}+4q mod 32 : conflict-free.
    __shared__ __align__(16) float vin[2][NB][96];
    // L1 input: u1[p][b][c][36] = chunk c holds k in [32c,32c+32), +4 pad.
    //   float4 at [c][4q] -> bank-quads {0,4,8,12}+4q mod 32 : conflict-free.
    __shared__ __align__(16) float u1[2][NB][4][36];

    const int tid  = threadIdx.x;
    const int b0   = blockIdx.x * NB;
    // waves 0-3 = L0, waves 4-7 = L1 -> each SIMD gets one of each
    const bool isL0 = tid < 256;
    const int t    = isL0 ? tid : tid - 256;
    const int c    = t & 3;          // K-chunk id == batch owned in cell phase
    const int rg   = t >> 2;         // state index j in [0,64)

    // ---- per-thread weights: 4 gate-rows {g*64+rg} x 1 chunk, ONE array (128 floats).
    //      (two arrays or >128 floats -> scratch spill: R3/R4 lesson) ----
    float4 wq[8][4];
    if (isL0) {
#pragma unroll
        for (int q = 0; q < 6; ++q)
#pragma unroll
            for (int g = 0; g < 4; ++g) {
                int r = g * 64 + rg;
                float tv[4];
#pragma unroll
                for (int e = 0; e < 4; ++e) {
                    int k = 24 * c + 4 * q + e;
                    tv[e] = (k < 32) ? Wih0[r * D_IN + k] : Whh0[r * H + (k - 32)];
                }
                wq[q][g] = make_float4(tv[0], tv[1], tv[2], tv[3]);
            }
    } else {
#pragma unroll
        for (int q = 0; q < 8; ++q)
#pragma unroll
            for (int g = 0; g < 4; ++g) {
                int r = g * 64 + rg;
                float tv[4];
#pragma unroll
                for (int e = 0; e < 4; ++e) {
                    int k = 32 * c + 4 * q + e;
                    tv[e] = (k < 64) ? Wih1[r * H + k] : Whh1[r * H + (k - 64)];
                }
                wq[q][g] = make_float4(tv[0], tv[1], tv[2], tv[3]);
            }
    }

    // ---- biases for state rg (same for all batches); c_state for (rg, batch c) ----
    float bi, bf_, bg_, bo, cst = 0.f;
    if (isL0) {
        bi  = bih0[rg]       + bhh0[rg];
        bf_ = bih0[64 + rg]  + bhh0[64 + rg];
        bg_ = bih0[128 + rg] + bhh0[128 + rg];
        bo  = bih0[192 + rg] + bhh0[192 + rg];
    } else {
        bi  = bih1[rg]       + bhh1[rg];
        bf_ = bih1[64 + rg]  + bhh1[64 + rg];
        bg_ = bih1[128 + rg] + bhh1[128 + rg];
        bo  = bih1[192 + rg] + bhh1[192 + rg];
    }

    // x-prefetch owners: threads 128..255 cover (4 b x 32 k) of one timestep
    const bool isx = (tid >= 128 && tid < 256);
    const float* xp = nullptr;
    int xb = 0, xk = 0;
    if (isx) {
        int t2 = tid - 128;
        xb = t2 >> 5; xk = t2 & 31;
        xp = x + (size_t)(b0 + xb) * T_STEPS * D_IN + xk;
    }

    // ---- init parity 0 (and the h1 region of parity 1, read at it=1) ----
    if (tid < 256) vin[0][tid >> 6][32 + (tid & 63)] = 0.f;  // h0[-1] = 0
    for (int i = tid; i < 576; i += 512) ((float*)u1)[i] = 0.f;   // u1[0] whole
    for (int i = tid; i < 288; i += 512) {                        // u1[1] h1 chunks
        int b = i / 72, r = i % 72;
        (&u1[1][b][2][0])[r] = 0.f;
    }
    if (isx) vin[0][xb][xk] = xp[0];
    __syncthreads();

    for (int it = 0; it <= T_STEPS; ++it) {
        const int p = it & 1;

        // register-prefetch x_{it+1}
        float xpre = 0.f;
        const bool havex = isx && (it + 1 < T_STEPS);
        if (havex) xpre = xp[(size_t)(it + 1) * D_IN];

        const bool active = isL0 ? (it < T_STEPS) : (it >= 1);

        float acc[4][NB];
#pragma unroll
        for (int g = 0; g < 4; ++g)
#pragma unroll
            for (int b = 0; b < NB; ++b) acc[g][b] = 0.f;

        if (isL0) {
            if (it < T_STEPS) {
#pragma unroll
                for (int q = 0; q < 6; ++q) {
                    float4 v0 = *(const float4*)&vin[p][0][24 * c + 4 * q];
                    float4 v1 = *(const float4*)&vin[p][1][24 * c + 4 * q];
                    float4 v2 = *(const float4*)&vin[p][2][24 * c + 4 * q];
                    float4 v3 = *(const float4*)&vin[p][3][24 * c + 4 * q];
#pragma unroll
                    for (int g = 0; g < 4; ++g) {
                        float4 w = wq[q][g];
                        acc[g][0] = fmaf(w.x, v0.x, acc[g][0]);
                        acc[g][0] = fmaf(w.y, v0.y, acc[g][0]);
                        acc[g][0] = fmaf(w.z, v0.z, acc[g][0]);
                        acc[g][0] = fmaf(w.w, v0.w, acc[g][0]);
                        acc[g][1] = fmaf(w.x, v1.x, acc[g][1]);
                        acc[g][1] = fmaf(w.y, v1.y, acc[g][1]);
                        acc[g][1] = fmaf(w.z, v1.z, acc[g][1]);
                        acc[g][1] = fmaf(w.w, v1.w, acc[g][1]);
                        acc[g][2] = fmaf(w.x, v2.x, acc[g][2]);
                        acc[g][2] = fmaf(w.y, v2.y, acc[g][2]);
                        acc[g][2] = fmaf(w.z, v2.z, acc[g][2]);
                        acc[g][2] = fmaf(w.w, v2.w, acc[g][2]);
                        acc[g][3] = fmaf(w.x, v3.x, acc[g][3]);
                        acc[g][3] = fmaf(w.y, v3.y, acc[g][3]);
                        acc[g][3] = fmaf(w.z, v3.z, acc[g][3]);
                        acc[g][3] = fmaf(w.w, v3.w, acc[g][3]);
                    }
                }
            }
        } else {
            if (it >= 1) {
#pragma unroll
                for (int q = 0; q < 8; ++q) {
                    float4 v0 = *(const float4*)&u1[p][0][c][4 * q];
                    float4 v1 = *(const float4*)&u1[p][1][c][4 * q];
                    float4 v2 = *(const float4*)&u1[p][2][c][4 * q];
                    float4 v3 = *(const float4*)&u1[p][3][c][4 * q];
#pragma unroll
                    for (int g = 0; g < 4; ++g) {
                        float4 w = wq[q][g];
                        acc[g][0] = fmaf(w.x, v0.x, acc[g][0]);
                        acc[g][0] = fmaf(w.y, v0.y, acc[g][0]);
                        acc[g][0] = fmaf(w.z, v0.z, acc[g][0]);
                        acc[g][0] = fmaf(w.w, v0.w, acc[g][0]);
                        acc[g][1] = fmaf(w.x, v1.x, acc[g][1]);
                        acc[g][1] = fmaf(w.y, v1.y, acc[g][1]);
                        acc[g][1] = fmaf(w.z, v1.z, acc[g][1]);
                        acc[g][1] = fmaf(w.w, v1.w, acc[g][1]);
                        acc[g][2] = fmaf(w.x, v2.x, acc[g][2]);
                        acc[g][2] = fmaf(w.y, v2.y, acc[g][2]);
                        acc[g][2] = fmaf(w.z, v2.z, acc[g][2]);
                        acc[g][2] = fmaf(w.w, v2.w, acc[g][2]);
                        acc[g][3] = fmaf(w.x, v3.x, acc[g][3]);
                        acc[g][3] = fmaf(w.y, v3.y, acc[g][3]);
                        acc[g][3] = fmaf(w.z, v3.z, acc[g][3]);
                        acc[g][3] = fmaf(w.w, v3.w, acc[g][3]);
                    }
                }
            }
        }

        if (active) {
            // reduce each gate over the quad, keep batch c's value
#pragma unroll
            for (int g = 0; g < 4; ++g)
#pragma unroll
                for (int b = 0; b < NB; ++b) acc[g][b] = red4(acc[g][b]);
            float gi = sel4(acc[0], c) + bi;
            float gf = sel4(acc[1], c) + bf_;
            float gg = sel4(acc[2], c) + bg_;
            float go = sel4(acc[3], c) + bo;
            float cc = sigf(gf) * cst + sigf(gi) * tanhf_(gg);
            cst = cc;
            float hh = sigf(go) * tanhf_(cc);
            if (isL0) {
                vin[p ^ 1][c][32 + rg]          = hh;  // L0's next input
                u1[p ^ 1][c][rg >> 5][rg & 31]  = hh;  // L1 input (k = rg)
            } else {
                u1[p ^ 1][c][2 + (rg >> 5)][rg & 31] = hh;  // k = 64 + rg
            }
        }
        if (havex) vin[p ^ 1][xb][xk] = xpre;
        __syncthreads();   // the ONE barrier per step
    }

    // ---- final FC on h1[T-1] (last L1 write: it=512, parity 0 -> wrote u1[1]) ----
    if (tid < NB) {
        float s = bfc[0];
#pragma unroll
        for (int k = 0; k < H; ++k)
            s += u1[1][tid][2 + (k >> 5)][k & 31] * Wfc[k];
        out[b0 + tid] = s;
    }
}

extern "C" void kernel_launch(void* const* d_in, const int* in_sizes, int n_in,
                              void* d_out, int out_size, void* d_ws, size_t ws_size,
                              hipStream_t stream) {
    const float* x    = (const float*)d_in[0];
    const float* Wih0 = (const float*)d_in[1];
    const float* Whh0 = (const float*)d_in[2];
    const float* bih0 = (const float*)d_in[3];
    const float* bhh0 = (const float*)d_in[4];
    const float* Wih1 = (const float*)d_in[5];
    const float* Whh1 = (const float*)d_in[6];
    const float* bih1 = (const float*)d_in[7];
    const float* bhh1 = (const float*)d_in[8];
    const float* Wfc  = (const float*)d_in[9];
    const float* bfc  = (const float*)d_in[10];
    float* out = (float*)d_out;

    const int B = out_size;            // 1024
    dim3 grid(B / NB), block(512);
    hipLaunchKernelGGL(lstm2_fused, grid, block, 0, stream,
                       x, Wih0, Whh0, bih0, bhh0,
                       Wih1, Whh1, bih1, bhh1, Wfc, bfc, out);
}

// Round 7
// 4936.655 us; speedup vs baseline: 1.6811x; 1.6811x over previous
//
#include <hip/hip_runtime.h>

#define T_STEPS 512
#define D_IN    32
#define H       64
#define NB      4     // batch elements per block

// ---- DPP cross-lane add: sum over the 4 lanes of each quad (chunk id = lane&3) ----
template<int CTRL>
__device__ __forceinline__ float dpp_add(float v) {
    int m = __builtin_amdgcn_update_dpp(0, __float_as_int(v), CTRL, 0xf, 0xf, true);
    return v + __int_as_float(m);
}
__device__ __forceinline__ float red4(float v) {
    v = dpp_add<0xB1>(v);   // quad_perm [1,0,3,2] : + lane^1
    v = dpp_add<0x4E>(v);   // quad_perm [2,3,0,1] : + lane^2
    return v;
}

__device__ __forceinline__ float sigf(float x) {
    return 1.0f / (1.0f + __expf(-x));
}
__device__ __forceinline__ float tanhf_(float x) {
    float e = __expf(2.0f * x);
    return 1.0f - 2.0f / (e + 1.0f);
}

__global__ __launch_bounds__(512, 2)
void lstm2_fused(const float* __restrict__ x,
                 const float* __restrict__ Wih0, const float* __restrict__ Whh0,
                 const float* __restrict__ bih0, const float* __restrict__ bhh0,
                 const float* __restrict__ Wih1, const float* __restrict__ Whh1,
                 const float* __restrict__ bih1, const float* __restrict__ bhh1,
                 const float* __restrict__ Wfc,  const float* __restrict__ bfc,
                 float* __restrict__ out)
{
    // Double-buffered (parity) state. One barrier per step.
    __shared__ __align__(16) float vin[2][NB][96];
    __shared__ __align__(16) float u1[2][NB][4][36];

    const int tid  = threadIdx.x;
    const int b0   = blockIdx.x * NB;
    const bool isL0 = tid < 256;
    const int t    = isL0 ? tid : tid - 256;
    const int c    = t & 3;          // K-chunk id == batch owned in cell phase
    const int rg   = t >> 2;         // state index j in [0,64)

    // per-thread weights: 4 gate-rows {g*64+rg} x 1 chunk, ONE 128-float array.
    // (>128 floats or two arrays -> scratch: R3/R4. pointer into local array -> alloca spill: R6.)
    float4 wq[8][4];
    if (isL0) {
#pragma unroll
        for (int q = 0; q < 6; ++q)
#pragma unroll
            for (int g = 0; g < 4; ++g) {
                int r = g * 64 + rg;
                float tv[4];
#pragma unroll
                for (int e = 0; e < 4; ++e) {
                    int k = 24 * c + 4 * q + e;
                    tv[e] = (k < 32) ? Wih0[r * D_IN + k] : Whh0[r * H + (k - 32)];
                }
                wq[q][g] = make_float4(tv[0], tv[1], tv[2], tv[3]);
            }
    } else {
#pragma unroll
        for (int q = 0; q < 8; ++q)
#pragma unroll
            for (int g = 0; g < 4; ++g) {
                int r = g * 64 + rg;
                float tv[4];
#pragma unroll
                for (int e = 0; e < 4; ++e) {
                    int k = 32 * c + 4 * q + e;
                    tv[e] = (k < 64) ? Wih1[r * H + k] : Whh1[r * H + (k - 64)];
                }
                wq[q][g] = make_float4(tv[0], tv[1], tv[2], tv[3]);
            }
    }

    // biases for state rg; c_state for (rg, batch c)
    float bi, bf_, bg_, bo, cst = 0.f;
    if (isL0) {
        bi  = bih0[rg]       + bhh0[rg];
        bf_ = bih0[64 + rg]  + bhh0[64 + rg];
        bg_ = bih0[128 + rg] + bhh0[128 + rg];
        bo  = bih0[192 + rg] + bhh0[192 + rg];
    } else {
        bi  = bih1[rg]       + bhh1[rg];
        bf_ = bih1[64 + rg]  + bhh1[64 + rg];
        bg_ = bih1[128 + rg] + bhh1[128 + rg];
        bo  = bih1[192 + rg] + bhh1[192 + rg];
    }

    // x-prefetch owners: threads 128..255 cover (4 b x 32 k) of one timestep
    const bool isx = (tid >= 128 && tid < 256);
    const float* xp = nullptr;
    int xb = 0, xk = 0;
    if (isx) {
        int t2 = tid - 128;
        xb = t2 >> 5; xk = t2 & 31;
        xp = x + (size_t)(b0 + xb) * T_STEPS * D_IN + xk;
    }

    // init parity 0 (and the h1 region of parity 1, read at it=1)
    if (tid < 256) vin[0][tid >> 6][32 + (tid & 63)] = 0.f;  // h0[-1] = 0
    for (int i = tid; i < 576; i += 512) ((float*)u1)[i] = 0.f;   // u1[0] whole
    for (int i = tid; i < 288; i += 512) {                        // u1[1] h1 chunks
        int b = i / 72, r = i % 72;
        (&u1[1][b][2][0])[r] = 0.f;
    }
    if (isx) vin[0][xb][xk] = xp[0];
    __syncthreads();

    for (int it = 0; it <= T_STEPS; ++it) {
        const int p = it & 1;

        float xpre = 0.f;
        const bool havex = isx && (it + 1 < T_STEPS);
        if (havex) xpre = xp[(size_t)(it + 1) * D_IN];

        const bool active = isL0 ? (it < T_STEPS) : (it >= 1);

        float acc[4][NB];
#pragma unroll
        for (int g = 0; g < 4; ++g)
#pragma unroll
            for (int b = 0; b < NB; ++b) acc[g][b] = 0.f;

        if (isL0) {
            if (it < T_STEPS) {
#pragma unroll
                for (int q = 0; q < 6; ++q) {
                    float4 v0 = *(const float4*)&vin[p][0][24 * c + 4 * q];
                    float4 v1 = *(const float4*)&vin[p][1][24 * c + 4 * q];
                    float4 v2 = *(const float4*)&vin[p][2][24 * c + 4 * q];
                    float4 v3 = *(const float4*)&vin[p][3][24 * c + 4 * q];
#pragma unroll
                    for (int g = 0; g < 4; ++g) {
                        float4 w = wq[q][g];
                        acc[g][0] = fmaf(w.x, v0.x, acc[g][0]);
                        acc[g][0] = fmaf(w.y, v0.y, acc[g][0]);
                        acc[g][0] = fmaf(w.z, v0.z, acc[g][0]);
                        acc[g][0] = fmaf(w.w, v0.w, acc[g][0]);
                        acc[g][1] = fmaf(w.x, v1.x, acc[g][1]);
                        acc[g][1] = fmaf(w.y, v1.y, acc[g][1]);
                        acc[g][1] = fmaf(w.z, v1.z, acc[g][1]);
                        acc[g][1] = fmaf(w.w, v1.w, acc[g][1]);
                        acc[g][2] = fmaf(w.x, v2.x, acc[g][2]);
                        acc[g][2] = fmaf(w.y, v2.y, acc[g][2]);
                        acc[g][2] = fmaf(w.z, v2.z, acc[g][2]);
                        acc[g][2] = fmaf(w.w, v2.w, acc[g][2]);
                        acc[g][3] = fmaf(w.x, v3.x, acc[g][3]);
                        acc[g][3] = fmaf(w.y, v3.y, acc[g][3]);
                        acc[g][3] = fmaf(w.z, v3.z, acc[g][3]);
                        acc[g][3] = fmaf(w.w, v3.w, acc[g][3]);
                    }
                }
            }
        } else {
            if (it >= 1) {
#pragma unroll
                for (int q = 0; q < 8; ++q) {
                    float4 v0 = *(const float4*)&u1[p][0][c][4 * q];
                    float4 v1 = *(const float4*)&u1[p][1][c][4 * q];
                    float4 v2 = *(const float4*)&u1[p][2][c][4 * q];
                    float4 v3 = *(const float4*)&u1[p][3][c][4 * q];
#pragma unroll
                    for (int g = 0; g < 4; ++g) {
                        float4 w = wq[q][g];
                        acc[g][0] = fmaf(w.x, v0.x, acc[g][0]);
                        acc[g][0] = fmaf(w.y, v0.y, acc[g][0]);
                        acc[g][0] = fmaf(w.z, v0.z, acc[g][0]);
                        acc[g][0] = fmaf(w.w, v0.w, acc[g][0]);
                        acc[g][1] = fmaf(w.x, v1.x, acc[g][1]);
                        acc[g][1] = fmaf(w.y, v1.y, acc[g][1]);
                        acc[g][1] = fmaf(w.z, v1.z, acc[g][1]);
                        acc[g][1] = fmaf(w.w, v1.w, acc[g][1]);
                        acc[g][2] = fmaf(w.x, v2.x, acc[g][2]);
                        acc[g][2] = fmaf(w.y, v2.y, acc[g][2]);
                        acc[g][2] = fmaf(w.z, v2.z, acc[g][2]);
                        acc[g][2] = fmaf(w.w, v2.w, acc[g][2]);
                        acc[g][3] = fmaf(w.x, v3.x, acc[g][3]);
                        acc[g][3] = fmaf(w.y, v3.y, acc[g][3]);
                        acc[g][3] = fmaf(w.z, v3.z, acc[g][3]);
                        acc[g][3] = fmaf(w.w, v3.w, acc[g][3]);
                    }
                }
            }
        }

        if (active) {
            // reduce each gate over the quad
#pragma unroll
            for (int g = 0; g < 4; ++g)
#pragma unroll
                for (int b = 0; b < NB; ++b) acc[g][b] = red4(acc[g][b]);
            // lane picks batch c's value — constant indices only (no array pointer!)
            float gi = (c == 1) ? acc[0][1] : acc[0][0];
            gi       = (c == 2) ? acc[0][2] : gi;
            gi       = (c == 3) ? acc[0][3] : gi;
            float gf = (c == 1) ? acc[1][1] : acc[1][0];
            gf       = (c == 2) ? acc[1][2] : gf;
            gf       = (c == 3) ? acc[1][3] : gf;
            float gg = (c == 1) ? acc[2][1] : acc[2][0];
            gg       = (c == 2) ? acc[2][2] : gg;
            gg       = (c == 3) ? acc[2][3] : gg;
            float go = (c == 1) ? acc[3][1] : acc[3][0];
            go       = (c == 2) ? acc[3][2] : go;
            go       = (c == 3) ? acc[3][3] : go;
            gi += bi; gf += bf_; gg += bg_; go += bo;
            float cc = sigf(gf) * cst + sigf(gi) * tanhf_(gg);
            cst = cc;
            float hh = sigf(go) * tanhf_(cc);
            if (isL0) {
                vin[p ^ 1][c][32 + rg]          = hh;  // L0's next input
                u1[p ^ 1][c][rg >> 5][rg & 31]  = hh;  // L1 input (k = rg)
            } else {
                u1[p ^ 1][c][2 + (rg >> 5)][rg & 31] = hh;  // k = 64 + rg
            }
        }
        if (havex) vin[p ^ 1][xb][xk] = xpre;
        __syncthreads();   // the ONE barrier per step
    }

    // final FC on h1[T-1] (last L1 write: it=512, p=0 -> wrote u1[1])
    if (tid < NB) {
        float s = bfc[0];
#pragma unroll
        for (int k = 0; k < H; ++k)
            s += u1[1][tid][2 + (k >> 5)][k & 31] * Wfc[k];
        out[b0 + tid] = s;
    }
}

extern "C" void kernel_launch(void* const* d_in, const int* in_sizes, int n_in,
                              void* d_out, int out_size, void* d_ws, size_t ws_size,
                              hipStream_t stream) {
    const float* x    = (const float*)d_in[0];
    const float* Wih0 = (const float*)d_in[1];
    const float* Whh0 = (const float*)d_in[2];
    const float* bih0 = (const float*)d_in[3];
    const float* bhh0 = (const float*)d_in[4];
    const float* Wih1 = (const float*)d_in[5];
    const float* Whh1 = (const float*)d_in[6];
    const float* bih1 = (const float*)d_in[7];
    const float* bhh1 = (const float*)d_in[8];
    const float* Wfc  = (const float*)d_in[9];
    const float* bfc  = (const float*)d_in[10];
    float* out = (float*)d_out;

    const int B = out_size;            // 1024
    dim3 grid(B / NB), block(512);
    hipLaunchKernelGGL(lstm2_fused, grid, block, 0, stream,
                       x, Wih0, Whh0, bih0, bhh0,
                       Wih1, Whh1, bih1, bhh1, Wfc, bfc, out);
}

// Round 8
// 1044.083 us; speedup vs baseline: 7.9487x; 4.7282x over previous
//
#include <hip/hip_runtime.h>

#define T_STEPS 512
#define D_IN    32
#define H       64
#define NB      4     // batch elements per block

// ---- DPP cross-lane adds ----
template<int CTRL>
__device__ __forceinline__ float dpp_add(float v) {
    int m = __builtin_amdgcn_update_dpp(0, __float_as_int(v), CTRL, 0xf, 0xf, true);
    return v + __int_as_float(m);
}
__device__ __forceinline__ float red4(float v) {      // sum over 4-lane quad
    v = dpp_add<0xB1>(v);   // quad_perm [1,0,3,2]
    v = dpp_add<0x4E>(v);   // quad_perm [2,3,0,1]
    return v;
}
__device__ __forceinline__ float red8(float v) {      // sum over aligned 8-lane group
    v = dpp_add<0xB1>(v);
    v = dpp_add<0x4E>(v);
    v = dpp_add<0x141>(v);  // row_half_mirror: lane i += lane (7-i) in its 8-group
    return v;
}

__device__ __forceinline__ float sigf(float x) {
    return 1.0f / (1.0f + __expf(-x));
}
__device__ __forceinline__ float tanhf_(float x) {
    float e = __expf(2.0f * x);
    return 1.0f - 2.0f / (e + 1.0f);
}

__global__ __launch_bounds__(768, 3)
void lstm2_fused(const float* __restrict__ x,
                 const float* __restrict__ Wih0, const float* __restrict__ Whh0,
                 const float* __restrict__ bih0, const float* __restrict__ bhh0,
                 const float* __restrict__ Wih1, const float* __restrict__ Whh1,
                 const float* __restrict__ bih1, const float* __restrict__ bhh1,
                 const float* __restrict__ Wfc,  const float* __restrict__ bfc,
                 float* __restrict__ out)
{
    // Double-buffered (parity) state; ONE barrier per step.
    // vin[p][b] = { x_t (32), h0 (64) }: L0 chunk c reads float4 at 24c+4q ->
    //   banks 24c mod 32 = {0,24,16,8}+... conflict-free.
    __shared__ __align__(16) float vin[2][NB][96];
    // u1[p][b][c][20]: L1 input, chunk c holds k in [16c,16c+16), 4-float pad.
    //   float4 at [c][4q] -> 20c mod 32 = {0,20,8,28,16,4,24,12}: conflict-free.
    __shared__ __align__(16) float u1[2][NB][8][20];

    const int tid  = threadIdx.x;
    const int b0   = blockIdx.x * NB;
    // waves 0-3 = L0 (256 thr), waves 4-11 = L1 (512 thr): each SIMD 1 L0 + 2 L1
    const bool isL0 = tid < 256;
    const int cL0 = tid & 3, rgL0 = tid >> 2;           // L0: chunk 24, red4
    const int tL1 = tid - 256;
    const int cL1 = tL1 & 7, rgL1 = tL1 >> 3;           // L1: chunk 16, red8

    // ---- per-thread weights: ONE array (L0: 96 floats q0..5; L1: 64 floats q0..3).
    //      Rules learned: single array, <=~150 live floats, no pointers into
    //      locals, constant indices, declare+consume acc inside one branch. ----
    float4 wq[6][4];
    if (isL0) {
#pragma unroll
        for (int q = 0; q < 6; ++q)
#pragma unroll
            for (int g = 0; g < 4; ++g) {
                int r = g * 64 + rgL0;
                float tv[4];
#pragma unroll
                for (int e = 0; e < 4; ++e) {
                    int k = 24 * cL0 + 4 * q + e;
                    tv[e] = (k < 32) ? Wih0[r * D_IN + k] : Whh0[r * H + (k - 32)];
                }
                wq[q][g] = make_float4(tv[0], tv[1], tv[2], tv[3]);
            }
    } else {
#pragma unroll
        for (int q = 0; q < 4; ++q)
#pragma unroll
            for (int g = 0; g < 4; ++g) {
                int r = g * 64 + rgL1;
                float tv[4];
#pragma unroll
                for (int e = 0; e < 4; ++e) {
                    int k = 16 * cL1 + 4 * q + e;
                    tv[e] = (k < 64) ? Wih1[r * H + k] : Whh1[r * H + (k - 64)];
                }
                wq[q][g] = make_float4(tv[0], tv[1], tv[2], tv[3]);
            }
    }

    // biases + cell state (cell owners: all L0 threads; L1 threads with cL1<4)
    float bi = 0.f, bf_ = 0.f, bg_ = 0.f, bo = 0.f, cst = 0.f;
    if (isL0) {
        bi  = bih0[rgL0]       + bhh0[rgL0];
        bf_ = bih0[64 + rgL0]  + bhh0[64 + rgL0];
        bg_ = bih0[128 + rgL0] + bhh0[128 + rgL0];
        bo  = bih0[192 + rgL0] + bhh0[192 + rgL0];
    } else if (cL1 < 4) {
        bi  = bih1[rgL1]       + bhh1[rgL1];
        bf_ = bih1[64 + rgL1]  + bhh1[64 + rgL1];
        bg_ = bih1[128 + rgL1] + bhh1[128 + rgL1];
        bo  = bih1[192 + rgL1] + bhh1[192 + rgL1];
    }

    // x-prefetch owners: threads 640..767 cover (4 b x 32 k) of one timestep
    const bool isx = tid >= 640;
    int xb = 0, xk = 0;
    const float* xp = nullptr;
    if (isx) {
        int t2 = tid - 640;
        xb = t2 >> 5; xk = t2 & 31;
        xp = x + (size_t)(b0 + xb) * T_STEPS * D_IN + xk;
    }

    // ---- init: zero all of u1 (both parities), h-part of vin[0]; stage x_0 ----
    for (int i = tid; i < 2 * NB * 8 * 20; i += 768) ((float*)u1)[i] = 0.f;
    if (tid < 256) vin[0][tid >> 6][32 + (tid & 63)] = 0.f;
    if (isx) vin[0][xb][xk] = xp[0];
    __syncthreads();

    for (int it = 0; it <= T_STEPS; ++it) {
        const int p = it & 1;

        float xpre = 0.f;
        const bool havex = isx && (it + 1 < T_STEPS);
        if (havex) xpre = xp[(size_t)(it + 1) * D_IN];

        if (isL0) {
            if (it < T_STEPS) {
                float acc[4][NB];
#pragma unroll
                for (int g = 0; g < 4; ++g)
#pragma unroll
                    for (int b = 0; b < NB; ++b) acc[g][b] = 0.f;
#pragma unroll
                for (int q = 0; q < 6; ++q) {
                    float4 v0 = *(const float4*)&vin[p][0][24 * cL0 + 4 * q];
                    float4 v1 = *(const float4*)&vin[p][1][24 * cL0 + 4 * q];
                    float4 v2 = *(const float4*)&vin[p][2][24 * cL0 + 4 * q];
                    float4 v3 = *(const float4*)&vin[p][3][24 * cL0 + 4 * q];
#pragma unroll
                    for (int g = 0; g < 4; ++g) {
                        float4 w = wq[q][g];
                        acc[g][0] = fmaf(w.x, v0.x, acc[g][0]);
                        acc[g][0] = fmaf(w.y, v0.y, acc[g][0]);
                        acc[g][0] = fmaf(w.z, v0.z, acc[g][0]);
                        acc[g][0] = fmaf(w.w, v0.w, acc[g][0]);
                        acc[g][1] = fmaf(w.x, v1.x, acc[g][1]);
                        acc[g][1] = fmaf(w.y, v1.y, acc[g][1]);
                        acc[g][1] = fmaf(w.z, v1.z, acc[g][1]);
                        acc[g][1] = fmaf(w.w, v1.w, acc[g][1]);
                        acc[g][2] = fmaf(w.x, v2.x, acc[g][2]);
                        acc[g][2] = fmaf(w.y, v2.y, acc[g][2]);
                        acc[g][2] = fmaf(w.z, v2.z, acc[g][2]);
                        acc[g][2] = fmaf(w.w, v2.w, acc[g][2]);
                        acc[g][3] = fmaf(w.x, v3.x, acc[g][3]);
                        acc[g][3] = fmaf(w.y, v3.y, acc[g][3]);
                        acc[g][3] = fmaf(w.z, v3.z, acc[g][3]);
                        acc[g][3] = fmaf(w.w, v3.w, acc[g][3]);
                    }
                }
                // reduce + cell, in-branch (R5's spill-free shape)
#pragma unroll
                for (int g = 0; g < 4; ++g)
#pragma unroll
                    for (int b = 0; b < NB; ++b) acc[g][b] = red4(acc[g][b]);
                float gi = (cL0 == 1) ? acc[0][1] : acc[0][0];
                gi       = (cL0 == 2) ? acc[0][2] : gi;
                gi       = (cL0 == 3) ? acc[0][3] : gi;
                float gf = (cL0 == 1) ? acc[1][1] : acc[1][0];
                gf       = (cL0 == 2) ? acc[1][2] : gf;
                gf       = (cL0 == 3) ? acc[1][3] : gf;
                float gg = (cL0 == 1) ? acc[2][1] : acc[2][0];
                gg       = (cL0 == 2) ? acc[2][2] : gg;
                gg       = (cL0 == 3) ? acc[2][3] : gg;
                float go = (cL0 == 1) ? acc[3][1] : acc[3][0];
                go       = (cL0 == 2) ? acc[3][2] : go;
                go       = (cL0 == 3) ? acc[3][3] : go;
                gi += bi; gf += bf_; gg += bg_; go += bo;
                float cc = sigf(gf) * cst + sigf(gi) * tanhf_(gg);
                cst = cc;
                float hh = sigf(go) * tanhf_(cc);
                vin[p ^ 1][cL0][32 + rgL0]             = hh;  // L0 next input
                u1[p ^ 1][cL0][rgL0 >> 4][rgL0 & 15]   = hh;  // L1 input k=rgL0
            }
        } else {
            if (it >= 1) {
                float acc[4][NB];
#pragma unroll
                for (int g = 0; g < 4; ++g)
#pragma unroll
                    for (int b = 0; b < NB; ++b) acc[g][b] = 0.f;
#pragma unroll
                for (int q = 0; q < 4; ++q) {
                    float4 v0 = *(const float4*)&u1[p][0][cL1][4 * q];
                    float4 v1 = *(const float4*)&u1[p][1][cL1][4 * q];
                    float4 v2 = *(const float4*)&u1[p][2][cL1][4 * q];
                    float4 v3 = *(const float4*)&u1[p][3][cL1][4 * q];
#pragma unroll
                    for (int g = 0; g < 4; ++g) {
                        float4 w = wq[q][g];
                        acc[g][0] = fmaf(w.x, v0.x, acc[g][0]);
                        acc[g][0] = fmaf(w.y, v0.y, acc[g][0]);
                        acc[g][0] = fmaf(w.z, v0.z, acc[g][0]);
                        acc[g][0] = fmaf(w.w, v0.w, acc[g][0]);
                        acc[g][1] = fmaf(w.x, v1.x, acc[g][1]);
                        acc[g][1] = fmaf(w.y, v1.y, acc[g][1]);
                        acc[g][1] = fmaf(w.z, v1.z, acc[g][1]);
                        acc[g][1] = fmaf(w.w, v1.w, acc[g][1]);
                        acc[g][2] = fmaf(w.x, v2.x, acc[g][2]);
                        acc[g][2] = fmaf(w.y, v2.y, acc[g][2]);
                        acc[g][2] = fmaf(w.z, v2.z, acc[g][2]);
                        acc[g][2] = fmaf(w.w, v2.w, acc[g][2]);
                        acc[g][3] = fmaf(w.x, v3.x, acc[g][3]);
                        acc[g][3] = fmaf(w.y, v3.y, acc[g][3]);
                        acc[g][3] = fmaf(w.z, v3.z, acc[g][3]);
                        acc[g][3] = fmaf(w.w, v3.w, acc[g][3]);
                    }
                }
#pragma unroll
                for (int g = 0; g < 4; ++g)
#pragma unroll
                    for (int b = 0; b < NB; ++b) acc[g][b] = red8(acc[g][b]);
                if (cL1 < 4) {
                    float gi = (cL1 == 1) ? acc[0][1] : acc[0][0];
                    gi       = (cL1 == 2) ? acc[0][2] : gi;
                    gi       = (cL1 == 3) ? acc[0][3] : gi;
                    float gf = (cL1 == 1) ? acc[1][1] : acc[1][0];
                    gf       = (cL1 == 2) ? acc[1][2] : gf;
                    gf       = (cL1 == 3) ? acc[1][3] : gf;
                    float gg = (cL1 == 1) ? acc[2][1] : acc[2][0];
                    gg       = (cL1 == 2) ? acc[2][2] : gg;
                    gg       = (cL1 == 3) ? acc[2][3] : gg;
                    float go = (cL1 == 1) ? acc[3][1] : acc[3][0];
                    go       = (cL1 == 2) ? acc[3][2] : go;
                    go       = (cL1 == 3) ? acc[3][3] : go;
                    gi += bi; gf += bf_; gg += bg_; go += bo;
                    float cc = sigf(gf) * cst + sigf(gi) * tanhf_(gg);
                    cst = cc;
                    float hh = sigf(go) * tanhf_(cc);
                    u1[p ^ 1][cL1][4 + (rgL1 >> 4)][rgL1 & 15] = hh;  // k=64+rgL1
                }
            }
        }
        if (havex) vin[p ^ 1][xb][xk] = xpre;
        __syncthreads();   // the ONE barrier per step
    }

    // ---- final FC on h1[T-1] (last L1 update at it=512, p=0 -> wrote u1[1]) ----
    if (tid < NB) {
        float s = bfc[0];
#pragma unroll
        for (int k = 0; k < H; ++k)
            s += u1[1][tid][4 + (k >> 4)][k & 15] * Wfc[k];
        out[b0 + tid] = s;
    }
}

extern "C" void kernel_launch(void* const* d_in, const int* in_sizes, int n_in,
                              void* d_out, int out_size, void* d_ws, size_t ws_size,
                              hipStream_t stream) {
    const float* x    = (const float*)d_in[0];
    const float* Wih0 = (const float*)d_in[1];
    const float* Whh0 = (const float*)d_in[2];
    const float* bih0 = (const float*)d_in[3];
    const float* bhh0 = (const float*)d_in[4];
    const float* Wih1 = (const float*)d_in[5];
    const float* Whh1 = (const float*)d_in[6];
    const float* bih1 = (const float*)d_in[7];
    const float* bhh1 = (const float*)d_in[8];
    const float* Wfc  = (const float*)d_in[9];
    const float* bfc  = (const float*)d_in[10];
    float* out = (float*)d_out;

    const int B = out_size;            // 1024
    dim3 grid(B / NB), block(768);
    hipLaunchKernelGGL(lstm2_fused, grid, block, 0, stream,
                       x, Wih0, Whh0, bih0, bhh0,
                       Wih1, Whh1, bih1, bhh1, Wfc, bfc, out);
}